// Round 9
// baseline (815.918 us; speedup 1.0000x reference)
//
#include <hip/hip_runtime.h>
#include <cstdint>
#include <cstddef>

// ---------------------------------------------------------------------------
// y = x @ W^T + lb  [B=32768, C=2048], K=2048 ; GroupNorm(32 groups of 64) ;
// per-row min ; out[0,c,b,0] = mins[b] + final_bias[c].
//
// R9: B (=W) never touches LDS. With identity bj-mapping each XCD's blocks
// share one 1MB W-panel (L2-resident), so B-fragments are loaded straight
// from global into registers (8x global_load_dwordx4 per wave per K-tile,
// double-buffered, issued ONE FULL TILE ahead -> ~2900cy cover >> L2 lat).
// LDS holds A only (2 x 32KB). LDS reads/tile drop 192->128 per CU
// (1536cy < MFMA 2483cy) -> MFMA becomes the sole limiter.
// Per tile: {issue B-regs(t+1) | ds a03,a47 | Q1,Q3 | lgkm0+bar |
// stage A(t+2) (4 glds) | Q2,Q4 | vmcnt(12)+bar}. vmcnt never 0 mid-loop.
// Fragment content byte-identical to the LDS path -> same absmax.
// ---------------------------------------------------------------------------

#define AS1C(p) ((const __attribute__((address_space(1))) void*)(p))
#define AS3(p)  ((__attribute__((address_space(3))) void*)(p))
#define SB0()   __builtin_amdgcn_sched_barrier(0)

typedef short  short8  __attribute__((ext_vector_type(8)));
typedef int    int4v   __attribute__((ext_vector_type(4)));
typedef float  f32x4   __attribute__((ext_vector_type(4)));
typedef unsigned short ushort8 __attribute__((ext_vector_type(8)));

static constexpr int BDIM = 32768;
static constexpr int KDIM = 2048;
static constexpr int CDIM = 2048;
static constexpr int NT   = KDIM / 64;    // 32 K-tiles of BK=64

// ----------------------------- helpers -------------------------------------

__device__ __forceinline__ unsigned short f2bf(float f) {
    unsigned u = __float_as_uint(f);
    u += 0x7FFFu + ((u >> 16) & 1u);   // RNE
    return (unsigned short)(u >> 16);
}

__device__ __forceinline__ unsigned enc_min(float f) {
    unsigned u = __float_as_uint(f);
    return (u & 0x80000000u) ? ~u : (u | 0x80000000u);  // monotone float->uint
}

__device__ __forceinline__ float dec_min(unsigned e) {
    unsigned u = (e & 0x80000000u) ? (e ^ 0x80000000u) : ~e;
    return __uint_as_float(u);
}

// ----------------------------- k1: convert ---------------------------------

__global__ void convert_kernel(const float* __restrict__ src,
                               unsigned short* __restrict__ dst, int n8) {
    int i = blockIdx.x * blockDim.x + threadIdx.x;
    if (i >= n8) return;
    const float4* s4 = (const float4*)src;
    float4 a = s4[2 * i];
    float4 b = s4[2 * i + 1];
    ushort8 o;
    o[0] = f2bf(a.x); o[1] = f2bf(a.y); o[2] = f2bf(a.z); o[3] = f2bf(a.w);
    o[4] = f2bf(b.x); o[5] = f2bf(b.y); o[6] = f2bf(b.z); o[7] = f2bf(b.w);
    ((ushort8*)dst)[i] = o;
}

// ------------------- k2: fused GEMM + GroupNorm + row-min -------------------
// 256x256 tile, BK=64, 8 waves 2Mx4N (wave owns 128x64 = one GN group).

__global__ __launch_bounds__(512, 2) void gemm_gn_min(
    const unsigned short* __restrict__ Abf,   // x [32768,2048] bf16
    const unsigned short* __restrict__ Wbf,   // W [2048,2048]  bf16
    const float* __restrict__ lb,
    const float* __restrict__ gw,
    const float* __restrict__ gb,
    unsigned int* mins_enc)
{
    // buf d (32 KB): A only, 256 rows x 128 B
    __shared__ unsigned char lds[65536];

    const int tid  = threadIdx.x;
    const int wid  = tid >> 6;
    const int lane = tid & 63;

    // identity mapping: XCD = blk%8 = bj -> W-panel (1MB) L2-resident per XCD.
    const int bj  = blockIdx.x & 7;           // C/256 = 8
    const int bi  = blockIdx.x >> 3;          // B/256 = 128
    const int row0 = bi * 256, col0 = bj * 256;
    const int wr = wid >> 2, wc = wid & 3;

    const int lrow = lane & 15;
    const int lq   = lane >> 4;
    const int lx   = lane & 7;    // read-side XOR (== r&7 of every frag row)

    // ---- A staging (proven R3 scheme): linear LDS dest, inverse-swizzled
    // global source; physical chunk p of LDS row r holds logical p^(r&7).
    const int schunk = (lane & 7) ^ (lane >> 3);
    const unsigned short* aSrc =
        Abf + (size_t)(row0 + wid * 16 + (lane >> 3)) * KDIM + schunk * 8;

    auto stageAh = [&](int d, int kt, int h) {
#pragma unroll
        for (int s = 0; s < 2; ++s)
            __builtin_amdgcn_global_load_lds(
                AS1C(aSrc + (size_t)(h * 128 + s * 8) * KDIM + kt * 64),
                AS3(&lds[d * 32768 + (h * 128 + wid * 16 + s * 8) * 128]),
                16, 0, 0);
    };

    auto rdA = [&](int d, int r, int ch) -> int4v {
        return *(const int4v*)&lds[d * 32768 + r * 128 + ((ch) ^ lx) * 16];
    };

    // ---- B fragments direct from global (L2): lane holds
    // W[col0 + wc*64 + n*16 + lrow][t*64 + ks*32 + lq*8 ..+8] -- byte-
    // identical to the old LDS-path fragment content.
    const unsigned short* bBase =
        Wbf + (size_t)(col0 + wc * 64 + lrow) * KDIM + lq * 8;
    auto loadB = [&](int4v (&dst)[4][2], int t) {
#pragma unroll
        for (int n = 0; n < 4; ++n)
#pragma unroll
            for (int ks = 0; ks < 2; ++ks)
                dst[n][ks] = *(const int4v*)(bBase + (size_t)n * 16 * KDIM +
                                             t * 64 + ks * 32);
    };

    f32x4 acc[8][4] = {};
    int4v a03[4][2], a47[4][2];
    int4v bA[4][2], bB[4][2];     // named double-buffer (static indexing)

    // ---- prologue: B(0)->bA (8), stage A(0) (4), B(1)->bB (8), A(1) (4).
    // vmcnt(12): A(0) landed (12 younger: B(1)+A(1)); the rest stay in flight.
    loadB(bA, 0);
    SB0();
    stageAh(0, 0, 0); stageAh(0, 0, 1);
    SB0();
    loadB(bB, 1);
    SB0();
    stageAh(1, 1, 0); stageAh(1, 1, 1);
    SB0();
    asm volatile("s_waitcnt vmcnt(12)" ::: "memory");
    __builtin_amdgcn_s_barrier();
    asm volatile("" ::: "memory");

    auto ktile = [&](int t, int4v (&bc)[4][2], int4v (&bn)[4][2]) {
        const int c = t & 1;
        const bool stB = (t + 1 < NT);
        const bool stA = (t + 2 < NT);

        // -------- top: issue B-regs(t+1) (full-tile latency cover)
        if (stB) loadB(bn, t + 1);
        SB0();
        // -------- ds reads: a03 then a47 (a47 drains under Q1/Q3)
#pragma unroll
        for (int m = 0; m < 4; ++m)
#pragma unroll
            for (int ks = 0; ks < 2; ++ks)
                a03[m][ks] = rdA(c, wr * 128 + m * 16 + lrow, ks * 4 + lq);
        SB0();
#pragma unroll
        for (int m = 0; m < 4; ++m)
#pragma unroll
            for (int ks = 0; ks < 2; ++ks)
                a47[m][ks] = rdA(c, wr * 128 + (m + 4) * 16 + lrow, ks * 4 + lq);
        SB0();
        // -------- Q1: m0-3 x n0-1
        __builtin_amdgcn_s_setprio(1);
#pragma unroll
        for (int m = 0; m < 4; ++m)
#pragma unroll
            for (int n = 0; n < 2; ++n)
#pragma unroll
                for (int ks = 0; ks < 2; ++ks)
                    acc[m][n] = __builtin_amdgcn_mfma_f32_16x16x32_bf16(
                        __builtin_bit_cast(short8, a03[m][ks]),
                        __builtin_bit_cast(short8, bc[n][ks]),
                        acc[m][n], 0, 0, 0);
        __builtin_amdgcn_s_setprio(0);
        SB0();
        // -------- Q3: m0-3 x n2-3
        __builtin_amdgcn_s_setprio(1);
#pragma unroll
        for (int m = 0; m < 4; ++m)
#pragma unroll
            for (int n = 0; n < 2; ++n)
#pragma unroll
                for (int ks = 0; ks < 2; ++ks)
                    acc[m][n + 2] = __builtin_amdgcn_mfma_f32_16x16x32_bf16(
                        __builtin_bit_cast(short8, a03[m][ks]),
                        __builtin_bit_cast(short8, bc[n + 2][ks]),
                        acc[m][n + 2], 0, 0, 0);
        __builtin_amdgcn_s_setprio(0);
        SB0();
        // -------- mid: all reads of buf c drained chip-wide -> buf c free
        asm volatile("s_waitcnt lgkmcnt(0)" ::: "memory");
        __builtin_amdgcn_s_barrier();
        asm volatile("" ::: "memory");
        // -------- stage A(t+2) into buf c (4 gload_lds)
        if (stA) { stageAh(c, t + 2, 0); stageAh(c, t + 2, 1); }
        SB0();
        // -------- Q2: m4-7 x n0-1
        __builtin_amdgcn_s_setprio(1);
#pragma unroll
        for (int m = 0; m < 4; ++m)
#pragma unroll
            for (int n = 0; n < 2; ++n)
#pragma unroll
                for (int ks = 0; ks < 2; ++ks)
                    acc[m + 4][n] = __builtin_amdgcn_mfma_f32_16x16x32_bf16(
                        __builtin_bit_cast(short8, a47[m][ks]),
                        __builtin_bit_cast(short8, bc[n][ks]),
                        acc[m + 4][n], 0, 0, 0);
        __builtin_amdgcn_s_setprio(0);
        SB0();
        // -------- Q4: m4-7 x n2-3
        __builtin_amdgcn_s_setprio(1);
#pragma unroll
        for (int m = 0; m < 4; ++m)
#pragma unroll
            for (int n = 0; n < 2; ++n)
#pragma unroll
                for (int ks = 0; ks < 2; ++ks)
                    acc[m + 4][n + 2] = __builtin_amdgcn_mfma_f32_16x16x32_bf16(
                        __builtin_bit_cast(short8, a47[m][ks]),
                        __builtin_bit_cast(short8, bc[n + 2][ks]),
                        acc[m + 4][n + 2], 0, 0, 0);
        __builtin_amdgcn_s_setprio(0);
        SB0();
        // -------- boundary: A(t+1) landed (12/8 younger ops stay in flight)
        if (stB && stA) asm volatile("s_waitcnt vmcnt(12)" ::: "memory");
        else if (stB)   asm volatile("s_waitcnt vmcnt(8)" ::: "memory");
        else            asm volatile("s_waitcnt vmcnt(0)" ::: "memory");
        __builtin_amdgcn_s_barrier();
        asm volatile("" ::: "memory");
    };

    for (int t = 0; t < NT; t += 2) {
        ktile(t,     bA, bB);
        ktile(t + 1, bB, bA);
    }

    // ---- epilogue: +bias, groupnorm over this wave's 64-col group, row min
    float lbv[4], gwv[4], gbv[4];
    const int cbase = col0 + wc * 64 + lrow;
#pragma unroll
    for (int n = 0; n < 4; ++n) {
        int ch = cbase + n * 16;
        lbv[n] = lb[ch]; gwv[n] = gw[ch]; gbv[n] = gb[ch];
    }

#pragma unroll
    for (int m = 0; m < 8; ++m) {
#pragma unroll
        for (int i = 0; i < 4; ++i) {
            float v[4];
            float s1 = 0.f, s2 = 0.f;
#pragma unroll
            for (int n = 0; n < 4; ++n) {
                v[n] = acc[m][n][i] + lbv[n];
                s1 += v[n];
                s2 += v[n] * v[n];
            }
#pragma unroll
            for (int mask = 1; mask <= 8; mask <<= 1) {
                s1 += __shfl_xor(s1, mask, 64);
                s2 += __shfl_xor(s2, mask, 64);
            }
            float mean = s1 * (1.f / 64.f);
            float var  = s2 * (1.f / 64.f) - mean * mean;
            float rstd = rsqrtf(var + 1e-5f);
            float mn = 3.4e38f;
#pragma unroll
            for (int n = 0; n < 4; ++n) {
                float nv = (v[n] - mean) * rstd * gwv[n] + gbv[n];
                mn = fminf(mn, nv);
            }
#pragma unroll
            for (int mask = 1; mask <= 8; mask <<= 1)
                mn = fminf(mn, __shfl_xor(mn, mask, 64));
            if (lrow == 0) {
                int row = row0 + wr * 128 + m * 16 + lq * 4 + i;
                atomicMin(mins_enc + row, enc_min(mn));
            }
        }
    }
}

// --------------------------- k3: broadcast ----------------------------------

__global__ void finalize_kernel(const unsigned int* mins_enc,
                                const float* __restrict__ fb, float* out) {
    size_t t = (size_t)blockIdx.x * 256 + threadIdx.x;
    size_t flat = t * 4;                      // 4 consecutive b, same c
    int c = (int)(flat >> 15);
    if (c == 1088) return;                    // mins live here; fixup later
    int b = (int)(flat & 32767);
    uint4 e = *(const uint4*)(mins_enc + b);
    float bias = fb[c];
    float4 o;
    o.x = dec_min(e.x) + bias;
    o.y = dec_min(e.y) + bias;
    o.z = dec_min(e.z) + bias;
    o.w = dec_min(e.w) + bias;
    *(float4*)(out + flat) = o;
}

__global__ void fixup_kernel(const float* __restrict__ fb, float* out) {
    int b = blockIdx.x * 256 + threadIdx.x;
    size_t idx = (size_t)1088 * 32768 + b;
    unsigned e = ((const unsigned*)out)[idx];  // read own cell first
    out[idx] = dec_min(e) + fb[1088];
}

// ----------------------------- launcher -------------------------------------

extern "C" void kernel_launch(void* const* d_in, const int* in_sizes, int n_in,
                              void* d_out, int out_size, void* d_ws, size_t ws_size,
                              hipStream_t stream) {
    const float* x  = (const float*)d_in[0];
    const float* w  = (const float*)d_in[1];
    const float* lb = (const float*)d_in[2];
    const float* gw = (const float*)d_in[3];
    const float* gb = (const float*)d_in[4];
    const float* fb = (const float*)d_in[5];
    float* out = (float*)d_out;

    // scratch regions inside d_out (268 MB total):
    unsigned short* xb = (unsigned short*)d_out;                        // 128 MiB
    unsigned short* wb = (unsigned short*)((char*)d_out + 134217728);   //   8 MiB
    unsigned int* mins = (unsigned int*)((char*)d_out + (size_t)1088 * 32768 * 4);

    // k1: fp32 -> bf16
    {
        int n8 = (BDIM * KDIM) / 8;
        convert_kernel<<<(n8 + 255) / 256, 256, 0, stream>>>(x, xb, n8);
    }
    {
        int n8 = (CDIM * KDIM) / 8;
        convert_kernel<<<(n8 + 255) / 256, 256, 0, stream>>>(w, wb, n8);
    }

    // init encoded mins to 0xFFFFFFFF (>= every encoding)
    hipMemsetAsync((void*)mins, 0xFF, (size_t)BDIM * 4, stream);

    // k2: fused GEMM + GN + min  (256x256 tiles -> 128x8 = 1024 blocks)
    gemm_gn_min<<<dim3((BDIM / 256) * (CDIM / 256)), dim3(512), 0, stream>>>(
        xb, wb, lb, gw, gb, mins);

    // k3: broadcast (skips c==1088), then fixup c==1088
    finalize_kernel<<<(BDIM / 4) * CDIM / 256, 256, 0, stream>>>(mins, fb, out);
    fixup_kernel<<<BDIM / 256, 256, 0, stream>>>(fb, out);
}

// Round 10
// 409.882 us; speedup vs baseline: 1.9906x; 1.9906x over previous
//
#include <hip/hip_runtime.h>
#include <cstdint>
#include <cstddef>

// ---------------------------------------------------------------------------
// y = x @ W^T + lb  [B=32768, C=2048], K=2048 ; GroupNorm(32 groups of 64) ;
// per-row min ; out[0,c,b,0] = mins[b] + final_bias[c].
//
// R10: cross-boundary register prefetch. The R3-family plateau (~292us, 42%)
// is LDS-port/MFMA ALTERNATION: every quadrant gated on a just-issued read
// batch -> 8 waves' reads contend the port (~1150cy), then all MFMA while
// the port idles. Fix with zero extra registers: tile t's Q1 operands
// (a03,b01) are ds_read during tile t-1's MFMA windows (WAR-legal reg reuse).
// Per tile: {stage B(t+1) | rd a47,b23 | Q1 (ungated) | Q2 (lgkm-counted) |
// lgkm0+vmcnt0+bar (all stages >=half-tile cover) | stage A(t+2) |
// prefetch b01',a03'(t+1) | Q3,Q4 reg-only | bar (NO waitcnt)}.
// Port 1152cy/half fully under MFMA 1242cy/half -> per-tile ~2600-3100cy.
// ---------------------------------------------------------------------------

#define AS1C(p) ((const __attribute__((address_space(1))) void*)(p))
#define AS3(p)  ((__attribute__((address_space(3))) void*)(p))
#define SB0()   __builtin_amdgcn_sched_barrier(0)

typedef short  short8  __attribute__((ext_vector_type(8)));
typedef int    int4v   __attribute__((ext_vector_type(4)));
typedef float  f32x4   __attribute__((ext_vector_type(4)));
typedef unsigned short ushort8 __attribute__((ext_vector_type(8)));

static constexpr int BDIM = 32768;
static constexpr int KDIM = 2048;
static constexpr int CDIM = 2048;
static constexpr int NT   = KDIM / 64;    // 32 K-tiles of BK=64

// ----------------------------- helpers -------------------------------------

__device__ __forceinline__ unsigned short f2bf(float f) {
    unsigned u = __float_as_uint(f);
    u += 0x7FFFu + ((u >> 16) & 1u);   // RNE
    return (unsigned short)(u >> 16);
}

__device__ __forceinline__ unsigned enc_min(float f) {
    unsigned u = __float_as_uint(f);
    return (u & 0x80000000u) ? ~u : (u | 0x80000000u);  // monotone float->uint
}

__device__ __forceinline__ float dec_min(unsigned e) {
    unsigned u = (e & 0x80000000u) ? (e ^ 0x80000000u) : ~e;
    return __uint_as_float(u);
}

// ----------------------------- k1: convert ---------------------------------

__global__ void convert_kernel(const float* __restrict__ src,
                               unsigned short* __restrict__ dst, int n8) {
    int i = blockIdx.x * blockDim.x + threadIdx.x;
    if (i >= n8) return;
    const float4* s4 = (const float4*)src;
    float4 a = s4[2 * i];
    float4 b = s4[2 * i + 1];
    ushort8 o;
    o[0] = f2bf(a.x); o[1] = f2bf(a.y); o[2] = f2bf(a.z); o[3] = f2bf(a.w);
    o[4] = f2bf(b.x); o[5] = f2bf(b.y); o[6] = f2bf(b.z); o[7] = f2bf(b.w);
    ((ushort8*)dst)[i] = o;
}

// ------------------- k2: fused GEMM + GroupNorm + row-min -------------------
// 256x256 tile, BK=64, 8 waves 2Mx4N (wave owns 128x64 = one GN group).

__global__ __launch_bounds__(512, 2) void gemm_gn_min(
    const unsigned short* __restrict__ Abf,   // x [32768,2048] bf16
    const unsigned short* __restrict__ Wbf,   // W [2048,2048]  bf16
    const float* __restrict__ lb,
    const float* __restrict__ gw,
    const float* __restrict__ gb,
    unsigned int* mins_enc)
{
    // A[d] at d*32768 (256 rows x 128B); B[d] at 65536 + d*32768
    __shared__ unsigned char lds[131072];

    const int tid  = threadIdx.x;
    const int wid  = tid >> 6;
    const int lane = tid & 63;

    // identity mapping: XCD = blk%8 = bj -> W-panel L2-resident per XCD.
    const int bj  = blockIdx.x & 7;           // C/256 = 8
    const int bi  = blockIdx.x >> 3;          // B/256 = 128
    const int row0 = bi * 256, col0 = bj * 256;
    const int wr = wid >> 2, wc = wid & 3;

    const int lrow = lane & 15;
    const int lq   = lane >> 4;
    const int lx   = lane & 7;    // read-side XOR (== r&7 of every frag row)

    // ---- staging (proven R3 scheme): linear LDS dest, inverse-swizzled
    // global source; physical chunk p of LDS row r holds logical p^(r&7).
    const int schunk = (lane & 7) ^ (lane >> 3);
    const unsigned short* aSrc =
        Abf + (size_t)(row0 + wid * 16 + (lane >> 3)) * KDIM + schunk * 8;
    const unsigned short* bSrc =
        Wbf + (size_t)(col0 + wid * 16 + (lane >> 3)) * KDIM + schunk * 8;

    auto stageA = [&](int d, int kt) {            // whole A tile: 4 gload_lds
#pragma unroll
        for (int h = 0; h < 2; ++h)
#pragma unroll
            for (int s = 0; s < 2; ++s)
                __builtin_amdgcn_global_load_lds(
                    AS1C(aSrc + (size_t)(h * 128 + s * 8) * KDIM + kt * 64),
                    AS3(&lds[d * 32768 + (h * 128 + wid * 16 + s * 8) * 128]),
                    16, 0, 0);
    };
    auto stageB = [&](int d, int kt) {            // whole B tile: 4 gload_lds
#pragma unroll
        for (int h = 0; h < 2; ++h)
#pragma unroll
            for (int s = 0; s < 2; ++s)
                __builtin_amdgcn_global_load_lds(
                    AS1C(bSrc + (size_t)(h * 128 + s * 8) * KDIM + kt * 64),
                    AS3(&lds[65536 + d * 32768 +
                             (h * 128 + wid * 16 + s * 8) * 128]), 16, 0, 0);
    };

    auto rdA = [&](int d, int r, int ch) -> int4v {
        return *(const int4v*)&lds[d * 32768 + r * 128 + ((ch) ^ lx) * 16];
    };
    auto rdB = [&](int d, int r, int ch) -> int4v {
        return *(const int4v*)&lds[65536 + d * 32768 + r * 128 +
                                   ((ch) ^ lx) * 16];
    };

    f32x4 acc[8][4] = {};
    int4v a03[4][2], a47[4][2], b01[2][2], b23[2][2];

    // ---- prologue: stage tile 0, drain, read tile-0 Q1 operands, issue A(1)
    stageA(0, 0); stageB(0, 0);
    asm volatile("s_waitcnt vmcnt(0)" ::: "memory");
    __builtin_amdgcn_s_barrier();
    asm volatile("" ::: "memory");
#pragma unroll
    for (int m = 0; m < 4; ++m)
#pragma unroll
        for (int ks = 0; ks < 2; ++ks)
            a03[m][ks] = rdA(0, wr * 128 + m * 16 + lrow, ks * 4 + lq);
#pragma unroll
    for (int n = 0; n < 2; ++n)
#pragma unroll
        for (int ks = 0; ks < 2; ++ks)
            b01[n][ks] = rdB(0, wc * 64 + n * 16 + lrow, ks * 4 + lq);
    SB0();
    stageA(1, 1);                 // in-flight at tile-0 entry: A(1)
    SB0();

    for (int t = 0; t < NT; ++t) {
        const int c = t & 1, o = c ^ 1;
        const bool stB = (t + 1 < NT);
        const bool stA = (t + 2 < NT);

        // -------- entry: stage B(t+1) -> B[o]
        if (stB) stageB(o, t + 1);
        SB0();
        // -------- first-half reads: a47 (8) + b23 (4) from buf c
#pragma unroll
        for (int m = 0; m < 4; ++m)
#pragma unroll
            for (int ks = 0; ks < 2; ++ks)
                a47[m][ks] = rdA(c, wr * 128 + (m + 4) * 16 + lrow, ks * 4 + lq);
#pragma unroll
        for (int n = 0; n < 2; ++n)
#pragma unroll
            for (int ks = 0; ks < 2; ++ks)
                b23[n][ks] = rdB(c, wc * 64 + (n + 2) * 16 + lrow, ks * 4 + lq);
        SB0();
        // -------- Q1: a03 x b01 (prefetched -> ungated)
        __builtin_amdgcn_s_setprio(1);
#pragma unroll
        for (int m = 0; m < 4; ++m)
#pragma unroll
            for (int n = 0; n < 2; ++n)
#pragma unroll
                for (int ks = 0; ks < 2; ++ks)
                    acc[m][n] = __builtin_amdgcn_mfma_f32_16x16x32_bf16(
                        __builtin_bit_cast(short8, a03[m][ks]),
                        __builtin_bit_cast(short8, b01[n][ks]),
                        acc[m][n], 0, 0, 0);
        __builtin_amdgcn_s_setprio(0);
        SB0();
        // -------- Q2: a47 x b01 (compiler-counted lgkm on a47)
        __builtin_amdgcn_s_setprio(1);
#pragma unroll
        for (int m = 0; m < 4; ++m)
#pragma unroll
            for (int n = 0; n < 2; ++n)
#pragma unroll
                for (int ks = 0; ks < 2; ++ks)
                    acc[m + 4][n] = __builtin_amdgcn_mfma_f32_16x16x32_bf16(
                        __builtin_bit_cast(short8, a47[m][ks]),
                        __builtin_bit_cast(short8, b01[n][ks]),
                        acc[m + 4][n], 0, 0, 0);
        __builtin_amdgcn_s_setprio(0);
        SB0();
        // -------- mid: own reads drained; A(t+1),B(t+1) stages landed
        // (both have >= half-tile issue-to-wait cover ~2700cy > HBM lat)
        asm volatile("s_waitcnt lgkmcnt(0)" ::: "memory");
        asm volatile("s_waitcnt vmcnt(0)" ::: "memory");
        __builtin_amdgcn_s_barrier();
        asm volatile("" ::: "memory");
        // -------- stage A(t+2) -> A[c] (A[c] fully read by all waves)
        if (stA) stageA(c, t + 2);
        SB0();
        // -------- prefetch b01'(t+1) from B[o] (b01 regs free after Q2)
        if (stB) {
#pragma unroll
            for (int n = 0; n < 2; ++n)
#pragma unroll
                for (int ks = 0; ks < 2; ++ks)
                    b01[n][ks] = rdB(o, wc * 64 + n * 16 + lrow, ks * 4 + lq);
        }
        SB0();
        // -------- Q3: a03 x b23 (b23 drained at mid -> register-only)
        __builtin_amdgcn_s_setprio(1);
#pragma unroll
        for (int m = 0; m < 4; ++m)
#pragma unroll
            for (int n = 0; n < 2; ++n)
#pragma unroll
                for (int ks = 0; ks < 2; ++ks)
                    acc[m][n + 2] = __builtin_amdgcn_mfma_f32_16x16x32_bf16(
                        __builtin_bit_cast(short8, a03[m][ks]),
                        __builtin_bit_cast(short8, b23[n][ks]),
                        acc[m][n + 2], 0, 0, 0);
        __builtin_amdgcn_s_setprio(0);
        SB0();
        // -------- prefetch a03'(t+1) from A[o] (a03 regs free after Q3)
        if (stB) {
#pragma unroll
            for (int m = 0; m < 4; ++m)
#pragma unroll
                for (int ks = 0; ks < 2; ++ks)
                    a03[m][ks] = rdA(o, wr * 128 + m * 16 + lrow, ks * 4 + lq);
        }
        SB0();
        // -------- Q4: a47 x b23 (register-only; prefetches fly under)
        __builtin_amdgcn_s_setprio(1);
#pragma unroll
        for (int m = 0; m < 4; ++m)
#pragma unroll
            for (int n = 0; n < 2; ++n)
#pragma unroll
                for (int ks = 0; ks < 2; ++ks)
                    acc[m + 4][n + 2] = __builtin_amdgcn_mfma_f32_16x16x32_bf16(
                        __builtin_bit_cast(short8, a47[m][ks]),
                        __builtin_bit_cast(short8, b23[n][ks]),
                        acc[m + 4][n + 2], 0, 0, 0);
        __builtin_amdgcn_s_setprio(0);
        SB0();
        // -------- boundary: barrier WITHOUT waitcnt (prefetch ds_reads and
        // A(t+2) stage stay in flight; cross-wave hazards were settled at mid)
        __builtin_amdgcn_s_barrier();
        asm volatile("" ::: "memory");
    }

    // ---- epilogue: +bias, groupnorm over this wave's 64-col group, row min
    float lbv[4], gwv[4], gbv[4];
    const int cbase = col0 + wc * 64 + lrow;
#pragma unroll
    for (int n = 0; n < 4; ++n) {
        int ch = cbase + n * 16;
        lbv[n] = lb[ch]; gwv[n] = gw[ch]; gbv[n] = gb[ch];
    }

#pragma unroll
    for (int m = 0; m < 8; ++m) {
#pragma unroll
        for (int i = 0; i < 4; ++i) {
            float v[4];
            float s1 = 0.f, s2 = 0.f;
#pragma unroll
            for (int n = 0; n < 4; ++n) {
                v[n] = acc[m][n][i] + lbv[n];
                s1 += v[n];
                s2 += v[n] * v[n];
            }
#pragma unroll
            for (int mask = 1; mask <= 8; mask <<= 1) {
                s1 += __shfl_xor(s1, mask, 64);
                s2 += __shfl_xor(s2, mask, 64);
            }
            float mean = s1 * (1.f / 64.f);
            float var  = s2 * (1.f / 64.f) - mean * mean;
            float rstd = rsqrtf(var + 1e-5f);
            float mn = 3.4e38f;
#pragma unroll
            for (int n = 0; n < 4; ++n) {
                float nv = (v[n] - mean) * rstd * gwv[n] + gbv[n];
                mn = fminf(mn, nv);
            }
#pragma unroll
            for (int mask = 1; mask <= 8; mask <<= 1)
                mn = fminf(mn, __shfl_xor(mn, mask, 64));
            if (lrow == 0) {
                int row = row0 + wr * 128 + m * 16 + lq * 4 + i;
                atomicMin(mins_enc + row, enc_min(mn));
            }
        }
    }
}

// --------------------------- k3: broadcast ----------------------------------

__global__ void finalize_kernel(const unsigned int* mins_enc,
                                const float* __restrict__ fb, float* out) {
    size_t t = (size_t)blockIdx.x * 256 + threadIdx.x;
    size_t flat = t * 4;                      // 4 consecutive b, same c
    int c = (int)(flat >> 15);
    if (c == 1088) return;                    // mins live here; fixup later
    int b = (int)(flat & 32767);
    uint4 e = *(const uint4*)(mins_enc + b);
    float bias = fb[c];
    float4 o;
    o.x = dec_min(e.x) + bias;
    o.y = dec_min(e.y) + bias;
    o.z = dec_min(e.z) + bias;
    o.w = dec_min(e.w) + bias;
    *(float4*)(out + flat) = o;
}

__global__ void fixup_kernel(const float* __restrict__ fb, float* out) {
    int b = blockIdx.x * 256 + threadIdx.x;
    size_t idx = (size_t)1088 * 32768 + b;
    unsigned e = ((const unsigned*)out)[idx];  // read own cell first
    out[idx] = dec_min(e) + fb[1088];
}

// ----------------------------- launcher -------------------------------------

extern "C" void kernel_launch(void* const* d_in, const int* in_sizes, int n_in,
                              void* d_out, int out_size, void* d_ws, size_t ws_size,
                              hipStream_t stream) {
    const float* x  = (const float*)d_in[0];
    const float* w  = (const float*)d_in[1];
    const float* lb = (const float*)d_in[2];
    const float* gw = (const float*)d_in[3];
    const float* gb = (const float*)d_in[4];
    const float* fb = (const float*)d_in[5];
    float* out = (float*)d_out;

    // scratch regions inside d_out (268 MB total):
    unsigned short* xb = (unsigned short*)d_out;                        // 128 MiB
    unsigned short* wb = (unsigned short*)((char*)d_out + 134217728);   //   8 MiB
    unsigned int* mins = (unsigned int*)((char*)d_out + (size_t)1088 * 32768 * 4);

    // k1: fp32 -> bf16
    {
        int n8 = (BDIM * KDIM) / 8;
        convert_kernel<<<(n8 + 255) / 256, 256, 0, stream>>>(x, xb, n8);
    }
    {
        int n8 = (CDIM * KDIM) / 8;
        convert_kernel<<<(n8 + 255) / 256, 256, 0, stream>>>(w, wb, n8);
    }

    // init encoded mins to 0xFFFFFFFF (>= every encoding)
    hipMemsetAsync((void*)mins, 0xFF, (size_t)BDIM * 4, stream);

    // k2: fused GEMM + GN + min  (256x256 tiles -> 128x8 = 1024 blocks)
    gemm_gn_min<<<dim3((BDIM / 256) * (CDIM / 256)), dim3(512), 0, stream>>>(
        xb, wb, lb, gw, gb, mins);

    // k3: broadcast (skips c==1088), then fixup c==1088
    finalize_kernel<<<(BDIM / 4) * CDIM / 256, 256, 0, stream>>>(mins, fb, out);
    fixup_kernel<<<BDIM / 256, 256, 0, stream>>>(fb, out);
}